// Round 2
// baseline (1220.968 us; speedup 1.0000x reference)
//
#include <hip/hip_runtime.h>

typedef __attribute__((ext_vector_type(8))) short  short8;   // MFMA A/B frag (8 bf16)
typedef __attribute__((ext_vector_type(4))) short  short4v;  // 8B LDS store
typedef __attribute__((ext_vector_type(4))) float  float4v;  // MFMA C/D frag
typedef __attribute__((ext_vector_type(4))) float  float4a;  // 16B global load

#define SEQ   2048
#define DHEAD 128
#define NH    32
#define NB    2
#define BM    64      // q rows per block (16 per wave x 4 waves)
#define BN    64      // k cols per tile

#define NEG_BIG (-1e30f)

__device__ __forceinline__ unsigned short f2bf(float x) {
    union { float f; unsigned int u; } un; un.f = x;
    unsigned int r = un.u + 0x7fffu + ((un.u >> 16) & 1u);   // round-to-nearest-even
    return (unsigned short)(r >> 16);
}

// XOR swizzle: permutes 16B slots within each 128B bank-row as a function of row.
// Balanced for all access patterns here (b128 frag reads, b64 staging writes).
__device__ __forceinline__ int swz(int row, int colb) {
    return colb ^ ((((row & 7) ^ ((row >> 3) & 7)) << 4));
}

// Flash attention, causal. fp32 in/out, bf16 MFMA 16x16x32.
// R2 changes vs R1:
//  - 2-phase pipeline: next tile's K/V global loads are issued into registers
//    right after the current tile's LDS writes; conversion+LDS-write happens
//    next iteration. Load latency hides under S/softmax/PV + barriers.
//  - XCD-chunked block swizzle: physical block p -> logical (p&7)*256 + (p>>3)
//    so each XCD owns 8 consecutive bh; sibling blocks of one bh share K/V
//    tiles through that XCD's L2 instead of thrashing across chiplets.
// Fragment layouts (guide §3, harness-verified):
//   A-frag: A[m = lane&15][k = (lane>>4)*8 + j]
//   B-frag: B[k = (lane>>4)*8 + j][n = lane&15]
//   C/D   : D[row = (lane>>4)*4 + reg][col = lane&15]
__global__ __launch_bounds__(256, 4)
void attn_fwd(const float* __restrict__ Qg,
              const float* __restrict__ Kg,
              const float* __restrict__ Vg,
              float* __restrict__ Og)
{
    // sK [64 key][128 d] bf16, 256B/row, swizzled          = 16384 B
    // sV [128 d][64 key] bf16 (V^T), 128B/row, swizzled    = 16384 B
    // sP 4 waves x [16 q][64 key] bf16, swizzled           =  8192 B
    // sQ overlays sV (only used before the main loop)       total 40960 B -> 4 blocks/CU
    __shared__ __align__(16) char smem[40960];
    char* sKb = smem;
    char* sVb = smem + 16384;
    char* sPb = smem + 32768;
    char* sQb = sVb;

    const int tid  = threadIdx.x;
    const int w    = tid >> 6;
    const int lane = tid & 63;
    const int quad = lane >> 4;
    const int m16  = lane & 15;

    // XCD-chunked swizzle (grid = 2048 = 8 XCD * 256, bijective)
    const int p  = blockIdx.x;
    const int lb = ((p & 7) << 8) | (p >> 3);
    const int qt = (SEQ / BM - 1) - (lb & 31);   // heavy q-tiles first within each bh
    const int bh = lb >> 5;                      // b*NH + h
    const int q0 = qt * BM;

    const float* Qp = Qg + (size_t)bh * SEQ * DHEAD;
    const float* Kp = Kg + (size_t)bh * SEQ * DHEAD;
    const float* Vp = Vg + (size_t)bh * SEQ * DHEAD;

    // per-thread staging geometry (constant across iterations)
    const int c4  = (tid & 31) << 2;   // K: float column
    const int r0  = tid >> 5;          // K: base row
    const int db  = tid & 31;          // V: d block of 4
    const int kb0 = tid >> 5;          // V: base key-block of 4

    // ---- stage Q once (fp32 -> bf16, swizzled, b64 stores) ----
    for (int i = tid; i < BM * 32; i += 256) {
        int r   = i >> 5;
        int qc4 = (i & 31) << 2;
        float4a v = *(const float4a*)(Qp + (size_t)(q0 + r) * DHEAD + qc4);
        short4v t;
        t[0] = (short)f2bf(v[0]); t[1] = (short)f2bf(v[1]);
        t[2] = (short)f2bf(v[2]); t[3] = (short)f2bf(v[3]);
        *(short4v*)(sQb + r * 256 + swz(r, qc4 * 2)) = t;
    }

    // ---- issue prefetch for k-tile 0 (lands during Q-frag setup) ----
    float4a kpre[8];
    float4a vpre[8];
#pragma unroll
    for (int j = 0; j < 8; ++j)
        kpre[j] = *(const float4a*)(Kp + (size_t)(r0 + j * 8) * DHEAD + c4);
#pragma unroll
    for (int it = 0; it < 2; ++it)
#pragma unroll
        for (int s = 0; s < 4; ++s)
            vpre[it * 4 + s] = *(const float4a*)(Vp + (size_t)((kb0 + it * 8) * 4 + s) * DHEAD + db * 4);

    __syncthreads();

    // Q B-frags live in registers for the whole kernel (one q-row per lane)
    short8 qf[4];
    const int qrow = w * 16 + m16;
#pragma unroll
    for (int kc = 0; kc < 4; ++kc)
        qf[kc] = *(const short8*)(sQb + qrow * 256 + swz(qrow, kc * 64 + quad * 16));

    float4v accO[8];
#pragma unroll
    for (int i = 0; i < 8; ++i) accO[i] = (float4v){0.f, 0.f, 0.f, 0.f};
    float mst = NEG_BIG, lst = 0.f;              // per-lane state for q = qglob
    const float scale = 0.08838834764831845f;    // 1/sqrt(128)
    const int   qglob = q0 + w * 16 + m16;

    for (int kt = 0; kt <= qt; ++kt) {
        const int k0 = kt * BN;
        __syncthreads();   // prior LDS reads (incl. qf at kt==0) done before restage

        // ---- write prefetched K tile (fp32 regs -> bf16 LDS, b64 swizzled) ----
#pragma unroll
        for (int j = 0; j < 8; ++j) {
            int r = r0 + j * 8;
            short4v t;
            t[0] = (short)f2bf(kpre[j][0]); t[1] = (short)f2bf(kpre[j][1]);
            t[2] = (short)f2bf(kpre[j][2]); t[3] = (short)f2bf(kpre[j][3]);
            *(short4v*)(sKb + r * 256 + swz(r, c4 * 2)) = t;
        }
        // ---- write prefetched V tile transposed (register 4x4 transpose) ----
#pragma unroll
        for (int it = 0; it < 2; ++it) {
            int kb = kb0 + it * 8;
#pragma unroll
            for (int c = 0; c < 4; ++c) {
                short4v t;
                t[0] = (short)f2bf(vpre[it * 4 + 0][c]);
                t[1] = (short)f2bf(vpre[it * 4 + 1][c]);
                t[2] = (short)f2bf(vpre[it * 4 + 2][c]);
                t[3] = (short)f2bf(vpre[it * 4 + 3][c]);
                int row = db * 4 + c;                       // d index
                *(short4v*)(sVb + row * 128 + swz(row, kb * 8)) = t;
            }
        }

        // ---- issue prefetch for next k-tile; latency hides under compute ----
        if (kt < qt) {
            const int k0n = k0 + BN;
#pragma unroll
            for (int j = 0; j < 8; ++j)
                kpre[j] = *(const float4a*)(Kp + (size_t)(k0n + r0 + j * 8) * DHEAD + c4);
#pragma unroll
            for (int it = 0; it < 2; ++it)
#pragma unroll
                for (int s = 0; s < 4; ++s)
                    vpre[it * 4 + s] = *(const float4a*)(Vp + (size_t)(k0n + (kb0 + it * 8) * 4 + s) * DHEAD + db * 4);
        }
        __syncthreads();

        // ---- S^T = K Q^T: accS[nt][r] = S[q=qglob][key = k0 + nt*16 + quad*4 + r] ----
        float4v accS[4];
#pragma unroll
        for (int nt = 0; nt < 4; ++nt) accS[nt] = (float4v){0.f, 0.f, 0.f, 0.f};
#pragma unroll
        for (int kc = 0; kc < 4; ++kc)
#pragma unroll
            for (int nt = 0; nt < 4; ++nt) {
                int krow = nt * 16 + m16;
                short8 kf = *(const short8*)(sKb + krow * 256 + swz(krow, kc * 64 + quad * 16));
                accS[nt] = __builtin_amdgcn_mfma_f32_16x16x32_bf16(kf, qf[kc], accS[nt], 0, 0, 0);
            }

        // ---- scale + causal mask (diagonal tile only) ----
        if (kt == qt) {
#pragma unroll
            for (int nt = 0; nt < 4; ++nt)
#pragma unroll
                for (int r = 0; r < 4; ++r) {
                    int key = k0 + nt * 16 + quad * 4 + r;
                    float s = accS[nt][r] * scale;
                    accS[nt][r] = (key > qglob) ? NEG_BIG : s;
                }
        } else {
#pragma unroll
            for (int nt = 0; nt < 4; ++nt)
#pragma unroll
                for (int r = 0; r < 4; ++r) accS[nt][r] *= scale;
        }

        // ---- online softmax: 16 in-lane values, cross-quad via shfl_xor 16/32 ----
        float mx = accS[0][0];
#pragma unroll
        for (int nt = 0; nt < 4; ++nt)
#pragma unroll
            for (int r = 0; r < 4; ++r) mx = fmaxf(mx, accS[nt][r]);
        mx = fmaxf(mx, __shfl_xor(mx, 16));
        mx = fmaxf(mx, __shfl_xor(mx, 32));
        float mnew  = fmaxf(mst, mx);
        float alpha = __expf(mst - mnew);
        mst = mnew;
        float rs = 0.f;
#pragma unroll
        for (int nt = 0; nt < 4; ++nt)
#pragma unroll
            for (int r = 0; r < 4; ++r) {
                float p2 = __expf(accS[nt][r] - mnew);
                accS[nt][r] = p2;
                rs += p2;
            }
        rs += __shfl_xor(rs, 16);
        rs += __shfl_xor(rs, 32);
        lst = lst * alpha + rs;

        // ---- rescale O (alpha for C-row quad*4+r lives at lane with m16 == quad*4+r) ----
        float alphaO[4];
#pragma unroll
        for (int r = 0; r < 4; ++r)
            alphaO[r] = __shfl(alpha, (quad << 4) | (quad * 4 + r));
#pragma unroll
        for (int dt = 0; dt < 8; ++dt)
#pragma unroll
            for (int r = 0; r < 4; ++r) accO[dt][r] *= alphaO[r];

        // ---- P -> per-wave LDS (4x b64 stores), read back as A-frags ----
        char* pwb = sPb + w * 2048;
#pragma unroll
        for (int nt = 0; nt < 4; ++nt) {
            short4v t;
            t[0] = (short)f2bf(accS[nt][0]); t[1] = (short)f2bf(accS[nt][1]);
            t[2] = (short)f2bf(accS[nt][2]); t[3] = (short)f2bf(accS[nt][3]);
            *(short4v*)(pwb + m16 * 128 + swz(m16, nt * 32 + quad * 8)) = t;
        }
        short8 pf[2];
#pragma unroll
        for (int kc2 = 0; kc2 < 2; ++kc2)
            pf[kc2] = *(const short8*)(pwb + m16 * 128 + swz(m16, kc2 * 64 + quad * 16));

        // ---- O += P V ----
#pragma unroll
        for (int kc2 = 0; kc2 < 2; ++kc2)
#pragma unroll
            for (int dt = 0; dt < 8; ++dt) {
                int vrow = dt * 16 + m16;
                short8 vf = *(const short8*)(sVb + vrow * 128 + swz(vrow, kc2 * 64 + quad * 16));
                accO[dt] = __builtin_amdgcn_mfma_f32_16x16x32_bf16(pf[kc2], vf, accO[dt], 0, 0, 0);
            }
    }

    // ---- epilogue: out[b][q][h*128 + d], fp32 ----
    const int b = bh >> 5;
    const int h = bh & 31;
    float il = 1.0f / lst;
    float invlO[4];
#pragma unroll
    for (int r = 0; r < 4; ++r)
        invlO[r] = __shfl(il, (quad << 4) | (quad * 4 + r));
#pragma unroll
    for (int dt = 0; dt < 8; ++dt)
#pragma unroll
        for (int r = 0; r < 4; ++r) {
            int q = q0 + w * 16 + quad * 4 + r;
            int d = dt * 16 + m16;
            Og[(size_t)(b * SEQ + q) * (NH * DHEAD) + h * DHEAD + d] = accO[dt][r] * invlO[r];
        }
}

extern "C" void kernel_launch(void* const* d_in, const int* in_sizes, int n_in,
                              void* d_out, int out_size, void* d_ws, size_t ws_size,
                              hipStream_t stream) {
    const float* Q = (const float*)d_in[0];
    const float* K = (const float*)d_in[1];
    const float* V = (const float*)d_in[2];
    float* O = (float*)d_out;
    dim3 grid((SEQ / BM) * NB * NH);
    attn_fwd<<<grid, 256, 0, stream>>>(Q, K, V, O);
}

// Round 4
// 986.319 us; speedup vs baseline: 1.2379x; 1.2379x over previous
//
#include <hip/hip_runtime.h>

typedef __attribute__((ext_vector_type(8))) short  short8;   // MFMA A/B frag / 16B bf16 chunk
typedef __attribute__((ext_vector_type(4))) short  short4v;  // 8B store
typedef __attribute__((ext_vector_type(4))) float  float4v;  // MFMA C/D frag
typedef __attribute__((ext_vector_type(4))) float  float4a;  // 16B global load

#define SEQ   2048
#define DHEAD 128
#define NH    32
#define NB    2
#define NBH   (NB * NH)
#define BM    64      // q rows per block (16 per wave x 4 waves)
#define BN    64      // k cols per tile
#define NEL   ((size_t)NBH * SEQ * DHEAD)      // elements per tensor

#define NEG_BIG (-1e30f)

__device__ __forceinline__ unsigned short f2bf(float x) {
    union { float f; unsigned int u; } un; un.f = x;
    unsigned int r = un.u + 0x7fffu + ((un.u >> 16) & 1u);   // round-to-nearest-even
    return (unsigned short)(r >> 16);
}

// XOR swizzle of 16B slots within a 128B bank-row, keyed by row.
__device__ __forceinline__ int fsw(int row) { return (row & 7) ^ ((row >> 3) & 7); }
__device__ __forceinline__ int swz(int row, int colb) { return colb ^ (fsw(row) << 4); }

// ---------------- pre-pass 1: K fp32 -> bf16 elementwise ----------------
__global__ void conv_bf16(const float* __restrict__ in, unsigned short* __restrict__ out) {
    const size_t n4 = NEL / 4;
    size_t idx = (size_t)blockIdx.x * blockDim.x + threadIdx.x;
    size_t stride = (size_t)gridDim.x * blockDim.x;
    for (size_t i = idx; i < n4; i += stride) {
        float4a v = ((const float4a*)in)[i];
        short4v t;
        t[0] = (short)f2bf(v[0]); t[1] = (short)f2bf(v[1]);
        t[2] = (short)f2bf(v[2]); t[3] = (short)f2bf(v[3]);
        ((short4v*)out)[i] = t;
    }
}

// ---------------- pre-pass 2: V [bh][k][d] fp32 -> Vt [bh][d][k] bf16 ----------------
__global__ void transpose_v(const float* __restrict__ V, unsigned short* __restrict__ Vt) {
    __shared__ float sT[64 * 132];           // 64 keys x 128 d (+4 pad)
    const int tid = threadIdx.x;
    const int bh  = blockIdx.x >> 5;
    const int k0  = (blockIdx.x & 31) * 64;
    const float* Vp = V + (size_t)bh * SEQ * DHEAD;

    for (int i = tid; i < 64 * 32; i += 256) {
        int r  = i >> 5;
        int c4 = (i & 31) << 2;
        float4a v = *(const float4a*)(Vp + (size_t)(k0 + r) * DHEAD + c4);
        *(float4a*)(&sT[r * 132 + c4]) = v;
    }
    __syncthreads();

    const int d  = tid >> 1;            // 0..127
    const int kh = (tid & 1) * 32;      // 0 or 32
    unsigned short* dst = Vt + ((size_t)bh * DHEAD + d) * SEQ + k0 + kh;
#pragma unroll
    for (int g4 = 0; g4 < 8; ++g4) {
        short4v t;
#pragma unroll
        for (int c = 0; c < 4; ++c)
            t[c] = (short)f2bf(sT[(kh + g4 * 4 + c) * 132 + d]);
        *(short4v*)(dst + g4 * 4) = t;
    }
}

// ---------------- main: flash attention, causal ----------------
// K (bf16) and V^T (bf16) come pre-converted: hot-loop staging is 8x short8
// global loads + 8x b128 swizzled ds_writes per thread (no f2bf, no transpose).
// Register double-buffer: tile kt+1 loaded into 32 VGPRs right after the
// LDS-ready barrier; latency hides under S-matmul + softmax + PV.
// Fragment layouts (guide §3, harness-verified):
//   A-frag: A[m = lane&15][k = (lane>>4)*8 + j]
//   B-frag: B[k = (lane>>4)*8 + j][n = lane&15]
//   C/D   : D[row = (lane>>4)*4 + reg][col = lane&15]
__global__ __launch_bounds__(256, 4)
void attn_fwd(const float* __restrict__ Qg,
              const unsigned short* __restrict__ Kb,
              const unsigned short* __restrict__ Vt,
              float* __restrict__ Og)
{
    // sK [64 key][128 d] swz = 16 KB (Q staged here pre-loop)
    // sV [128 d][64 key] swz = 16 KB
    // sP 4 waves x [16 q][64 key] swz = 8 KB     total 40 KB -> 4 blocks/CU
    __shared__ __align__(16) char smem[40960];
    char* sKb = smem;
    char* sVb = smem + 16384;
    char* sPb = smem + 32768;
    char* sQb = sKb;

    const int tid  = threadIdx.x;
    const int w    = tid >> 6;
    const int lane = tid & 63;
    const int quad = lane >> 4;
    const int m16  = lane & 15;

    // XCD-chunked swizzle (grid = 2048 = 8 XCD * 256, bijective)
    const int p  = blockIdx.x;
    const int lb = ((p & 7) << 8) | (p >> 3);
    const int qt = (SEQ / BM - 1) - (lb & 31);   // heavy q-tiles first within each bh
    const int bh = lb >> 5;
    const int q0 = qt * BM;

    const float*          Qp = Qg + (size_t)bh * SEQ * DHEAD;
    const unsigned short* Kp = Kb + (size_t)bh * SEQ * DHEAD;
    const unsigned short* Vp = Vt + (size_t)bh * DHEAD * SEQ;

    // ---- stage Q once (fp32 -> bf16, swizzled) into sK region ----
    for (int i = tid; i < BM * 32; i += 256) {
        int r  = i >> 5;
        int c4 = (i & 31) << 2;
        float4a v = *(const float4a*)(Qp + (size_t)(q0 + r) * DHEAD + c4);
        short4v t;
        t[0] = (short)f2bf(v[0]); t[1] = (short)f2bf(v[1]);
        t[2] = (short)f2bf(v[2]); t[3] = (short)f2bf(v[3]);
        *(short4v*)(sQb + r * 256 + swz(r, c4 * 2)) = t;
    }
    __syncthreads();

    short8 qf[4];
    const int qrow = w * 16 + m16;
#pragma unroll
    for (int kc = 0; kc < 4; ++kc)
        qf[kc] = *(const short8*)(sQb + qrow * 256 + swz(qrow, kc * 64 + quad * 16));
    // NOTE: barrier at loop top covers these qf reads before K(0) overwrites sK.

    // ---- prefetch tile 0 into registers (8 x short8 = 32 VGPRs) ----
    short8 kbuf[4], vbuf[4];
#define LOAD_KV(K0)                                                                  \
    _Pragma("unroll")                                                                \
    for (int j_ = 0; j_ < 4; ++j_) {                                                 \
        int ik_ = tid + 256 * j_;                                                    \
        kbuf[j_] = *(const short8*)(Kp + (size_t)((K0) + (ik_ >> 4)) * DHEAD + (ik_ & 15) * 8); \
        vbuf[j_] = *(const short8*)(Vp + (size_t)(ik_ >> 3) * SEQ + (K0) + (ik_ & 7) * 8);     \
    }
#define WRITE_KV()                                                                   \
    _Pragma("unroll")                                                                \
    for (int j_ = 0; j_ < 4; ++j_) {                                                 \
        int ik_ = tid + 256 * j_;                                                    \
        int kr_ = ik_ >> 4, ks_ = ik_ & 15;                                          \
        *(short8*)(sKb + kr_ * 256 + swz(kr_, ks_ * 16)) = kbuf[j_];                 \
        int vr_ = ik_ >> 3, vs_ = ik_ & 7;                                           \
        *(short8*)(sVb + vr_ * 128 + swz(vr_, vs_ * 16)) = vbuf[j_];                 \
    }

    LOAD_KV(0);

    float4v accO[8];
#pragma unroll
    for (int i = 0; i < 8; ++i) accO[i] = (float4v){0.f, 0.f, 0.f, 0.f};
    float mst = NEG_BIG, lst = 0.f;
    const float scale = 0.08838834764831845f;   // 1/sqrt(128)
    const int   qglob = q0 + w * 16 + m16;

    for (int kt = 0; kt <= qt; ++kt) {
        const int k0 = kt * BN;
        __syncthreads();   // prev-iter LDS reads done (kt==0: qf reads done)

        WRITE_KV();        // regs (tile kt) -> swizzled LDS
        __syncthreads();   // tiles visible to all waves

        if (kt < qt) { LOAD_KV(k0 + BN); }   // prefetch kt+1; hides under compute

        // ---- S^T = K Q^T: accS[nt][r] = S[q=qglob][key = k0 + nt*16 + quad*4 + r] ----
        float4v accS[4];
#pragma unroll
        for (int nt = 0; nt < 4; ++nt) accS[nt] = (float4v){0.f, 0.f, 0.f, 0.f};
#pragma unroll
        for (int kc = 0; kc < 4; ++kc)
#pragma unroll
            for (int nt = 0; nt < 4; ++nt) {
                int krow = nt * 16 + m16;
                short8 kf = *(const short8*)(sKb + krow * 256 + swz(krow, kc * 64 + quad * 16));
                accS[nt] = __builtin_amdgcn_mfma_f32_16x16x32_bf16(kf, qf[kc], accS[nt], 0, 0, 0);
            }

        // ---- scale + causal mask (diagonal tile only) ----
        if (kt == qt) {
#pragma unroll
            for (int nt = 0; nt < 4; ++nt)
#pragma unroll
                for (int r = 0; r < 4; ++r) {
                    int key = k0 + nt * 16 + quad * 4 + r;
                    float s = accS[nt][r] * scale;
                    accS[nt][r] = (key > qglob) ? NEG_BIG : s;
                }
        } else {
#pragma unroll
            for (int nt = 0; nt < 4; ++nt)
#pragma unroll
                for (int r = 0; r < 4; ++r) accS[nt][r] *= scale;
        }

        // ---- online softmax (one q-row per lane; cross-quad via shfl_xor 16/32) ----
        float mx = accS[0][0];
#pragma unroll
        for (int nt = 0; nt < 4; ++nt)
#pragma unroll
            for (int r = 0; r < 4; ++r) mx = fmaxf(mx, accS[nt][r]);
        mx = fmaxf(mx, __shfl_xor(mx, 16));
        mx = fmaxf(mx, __shfl_xor(mx, 32));
        float mnew  = fmaxf(mst, mx);
        float alpha = __expf(mst - mnew);
        mst = mnew;
        float rs = 0.f;
#pragma unroll
        for (int nt = 0; nt < 4; ++nt)
#pragma unroll
            for (int r = 0; r < 4; ++r) {
                float p2 = __expf(accS[nt][r] - mnew);
                accS[nt][r] = p2;
                rs += p2;
            }
        rs += __shfl_xor(rs, 16);
        rs += __shfl_xor(rs, 32);
        lst = lst * alpha + rs;

        // ---- rescale O ----
        float alphaO[4];
#pragma unroll
        for (int r = 0; r < 4; ++r)
            alphaO[r] = __shfl(alpha, (quad << 4) | (quad * 4 + r));
#pragma unroll
        for (int dt = 0; dt < 8; ++dt)
#pragma unroll
            for (int r = 0; r < 4; ++r) accO[dt][r] *= alphaO[r];

        // ---- P -> per-wave LDS, read back as A-frags ----
        char* pwb = sPb + w * 2048;
#pragma unroll
        for (int nt = 0; nt < 4; ++nt) {
            short4v t;
            t[0] = (short)f2bf(accS[nt][0]); t[1] = (short)f2bf(accS[nt][1]);
            t[2] = (short)f2bf(accS[nt][2]); t[3] = (short)f2bf(accS[nt][3]);
            *(short4v*)(pwb + m16 * 128 + swz(m16, nt * 32 + quad * 8)) = t;
        }
        short8 pf[2];
#pragma unroll
        for (int kc2 = 0; kc2 < 2; ++kc2)
            pf[kc2] = *(const short8*)(pwb + m16 * 128 + swz(m16, kc2 * 64 + quad * 16));

        // ---- O += P V ----
#pragma unroll
        for (int kc2 = 0; kc2 < 2; ++kc2)
#pragma unroll
            for (int dt = 0; dt < 8; ++dt) {
                int vrow = dt * 16 + m16;
                short8 vf = *(const short8*)(sVb + vrow * 128 + swz(vrow, kc2 * 64 + quad * 16));
                accO[dt] = __builtin_amdgcn_mfma_f32_16x16x32_bf16(pf[kc2], vf, accO[dt], 0, 0, 0);
            }
    }

    // ---- epilogue: out[b][q][h*128 + d], fp32 ----
    const int b = bh >> 5;
    const int h = bh & 31;
    float il = 1.0f / lst;
    float invlO[4];
#pragma unroll
    for (int r = 0; r < 4; ++r)
        invlO[r] = __shfl(il, (quad << 4) | (quad * 4 + r));
#pragma unroll
    for (int dt = 0; dt < 8; ++dt)
#pragma unroll
        for (int r = 0; r < 4; ++r) {
            int q = q0 + w * 16 + quad * 4 + r;
            int d = dt * 16 + m16;
            Og[(size_t)(b * SEQ + q) * (NH * DHEAD) + h * DHEAD + d] = accO[dt][r] * invlO[r];
        }
}

// ---------------- fallback (R1 kernel, proven 746 us) if workspace too small ----------------
__global__ __launch_bounds__(256, 4)
void attn_legacy(const float* __restrict__ Qg, const float* __restrict__ Kg,
                 const float* __restrict__ Vg, float* __restrict__ Og)
{
    __shared__ __align__(16) char smem[40960];
    char* sKb = smem;
    char* sVb = smem + 16384;
    char* sPb = smem + 32768;
    char* sQb = sVb;

    const int tid  = threadIdx.x;
    const int w    = tid >> 6;
    const int lane = tid & 63;
    const int quad = lane >> 4;
    const int m16  = lane & 15;

    const int bid = blockIdx.x;
    const int qt  = (SEQ / BM - 1) - (bid & 31);
    const int bh  = bid >> 5;
    const int q0  = qt * BM;

    const float* Qp = Qg + (size_t)bh * SEQ * DHEAD;
    const float* Kp = Kg + (size_t)bh * SEQ * DHEAD;
    const float* Vp = Vg + (size_t)bh * SEQ * DHEAD;

    for (int i = tid; i < BM * 32; i += 256) {
        int r  = i >> 5;
        int c4 = (i & 31) << 2;
        float4a v = *(const float4a*)(Qp + (size_t)(q0 + r) * DHEAD + c4);
        short4v t;
        t[0] = (short)f2bf(v[0]); t[1] = (short)f2bf(v[1]);
        t[2] = (short)f2bf(v[2]); t[3] = (short)f2bf(v[3]);
        *(short4v*)(sQb + r * 256 + swz(r, c4 * 2)) = t;
    }
    __syncthreads();

    short8 qf[4];
    const int qrow = w * 16 + m16;
#pragma unroll
    for (int kc = 0; kc < 4; ++kc)
        qf[kc] = *(const short8*)(sQb + qrow * 256 + swz(qrow, kc * 64 + quad * 16));

    float4v accO[8];
#pragma unroll
    for (int i = 0; i < 8; ++i) accO[i] = (float4v){0.f, 0.f, 0.f, 0.f};
    float mst = NEG_BIG, lst = 0.f;
    const float scale = 0.08838834764831845f;
    const int   qglob = q0 + w * 16 + m16;

    for (int kt = 0; kt <= qt; ++kt) {
        const int k0 = kt * BN;
        __syncthreads();
        for (int i = tid; i < BN * 32; i += 256) {
            int r  = i >> 5;
            int c4 = (i & 31) << 2;
            float4a v = *(const float4a*)(Kp + (size_t)(k0 + r) * DHEAD + c4);
            short4v t;
            t[0] = (short)f2bf(v[0]); t[1] = (short)f2bf(v[1]);
            t[2] = (short)f2bf(v[2]); t[3] = (short)f2bf(v[3]);
            *(short4v*)(sKb + r * 256 + swz(r, c4 * 2)) = t;
        }
        for (int i = tid; i < 512; i += 256) {
            int kb = i >> 5;
            int db = i & 31;
            const float* src = Vp + (size_t)(k0 + kb * 4) * DHEAD + db * 4;
            float4a v0 = *(const float4a*)(src);
            float4a v1 = *(const float4a*)(src + DHEAD);
            float4a v2 = *(const float4a*)(src + 2 * DHEAD);
            float4a v3 = *(const float4a*)(src + 3 * DHEAD);
#pragma unroll
            for (int c = 0; c < 4; ++c) {
                short4v t;
                t[0] = (short)f2bf(v0[c]); t[1] = (short)f2bf(v1[c]);
                t[2] = (short)f2bf(v2[c]); t[3] = (short)f2bf(v3[c]);
                int row = db * 4 + c;
                *(short4v*)(sVb + row * 128 + swz(row, kb * 8)) = t;
            }
        }
        __syncthreads();

        float4v accS[4];
#pragma unroll
        for (int nt = 0; nt < 4; ++nt) accS[nt] = (float4v){0.f, 0.f, 0.f, 0.f};
#pragma unroll
        for (int kc = 0; kc < 4; ++kc)
#pragma unroll
            for (int nt = 0; nt < 4; ++nt) {
                int krow = nt * 16 + m16;
                short8 kf = *(const short8*)(sKb + krow * 256 + swz(krow, kc * 64 + quad * 16));
                accS[nt] = __builtin_amdgcn_mfma_f32_16x16x32_bf16(kf, qf[kc], accS[nt], 0, 0, 0);
            }

        if (kt == qt) {
#pragma unroll
            for (int nt = 0; nt < 4; ++nt)
#pragma unroll
                for (int r = 0; r < 4; ++r) {
                    int key = k0 + nt * 16 + quad * 4 + r;
                    float s = accS[nt][r] * scale;
                    accS[nt][r] = (key > qglob) ? NEG_BIG : s;
                }
        } else {
#pragma unroll
            for (int nt = 0; nt < 4; ++nt)
#pragma unroll
                for (int r = 0; r < 4; ++r) accS[nt][r] *= scale;
        }

        float mx = accS[0][0];
#pragma unroll
        for (int nt = 0; nt < 4; ++nt)
#pragma unroll
            for (int r = 0; r < 4; ++r) mx = fmaxf(mx, accS[nt][r]);
        mx = fmaxf(mx, __shfl_xor(mx, 16));
        mx = fmaxf(mx, __shfl_xor(mx, 32));
        float mnew  = fmaxf(mst, mx);
        float alpha = __expf(mst - mnew);
        mst = mnew;
        float rs = 0.f;
#pragma unroll
        for (int nt = 0; nt < 4; ++nt)
#pragma unroll
            for (int r = 0; r < 4; ++r) {
                float p2 = __expf(accS[nt][r] - mnew);
                accS[nt][r] = p2;
                rs += p2;
            }
        rs += __shfl_xor(rs, 16);
        rs += __shfl_xor(rs, 32);
        lst = lst * alpha + rs;

        float alphaO[4];
#pragma unroll
        for (int r = 0; r < 4; ++r)
            alphaO[r] = __shfl(alpha, (quad << 4) | (quad * 4 + r));
#pragma unroll
        for (int dt = 0; dt < 8; ++dt)
#pragma unroll
            for (int r = 0; r < 4; ++r) accO[dt][r] *= alphaO[r];

        char* pwb = sPb + w * 2048;
#pragma unroll
        for (int nt = 0; nt < 4; ++nt) {
            short4v t;
            t[0] = (short)f2bf(accS[nt][0]); t[1] = (short)f2bf(accS[nt][1]);
            t[2] = (short)f2bf(accS[nt][2]); t[3] = (short)f2bf(accS[nt][3]);
            *(short4v*)(pwb + m16 * 128 + swz(m16, nt * 32 + quad * 8)) = t;
        }
        short8 pf[2];
#pragma unroll
        for (int kc2 = 0; kc2 < 2; ++kc2)
            pf[kc2] = *(const short8*)(pwb + m16 * 128 + swz(m16, kc2 * 64 + quad * 16));

#pragma unroll
        for (int kc2 = 0; kc2 < 2; ++kc2)
#pragma unroll
            for (int dt = 0; dt < 8; ++dt) {
                int vrow = dt * 16 + m16;
                short8 vf = *(const short8*)(sVb + vrow * 128 + swz(vrow, kc2 * 64 + quad * 16));
                accO[dt] = __builtin_amdgcn_mfma_f32_16x16x32_bf16(pf[kc2], vf, accO[dt], 0, 0, 0);
            }
    }

    const int b = bh >> 5;
    const int h = bh & 31;
    float il = 1.0f / lst;
    float invlO[4];
#pragma unroll
    for (int r = 0; r < 4; ++r)
        invlO[r] = __shfl(il, (quad << 4) | (quad * 4 + r));
#pragma unroll
    for (int dt = 0; dt < 8; ++dt)
#pragma unroll
        for (int r = 0; r < 4; ++r) {
            int q = q0 + w * 16 + quad * 4 + r;
            int d = dt * 16 + m16;
            Og[(size_t)(b * SEQ + q) * (NH * DHEAD) + h * DHEAD + d] = accO[dt][r] * invlO[r];
        }
}

extern "C" void kernel_launch(void* const* d_in, const int* in_sizes, int n_in,
                              void* d_out, int out_size, void* d_ws, size_t ws_size,
                              hipStream_t stream) {
    const float* Q = (const float*)d_in[0];
    const float* K = (const float*)d_in[1];
    const float* V = (const float*)d_in[2];
    float* O = (float*)d_out;

    const size_t need = 2 * NEL * sizeof(unsigned short);   // Kb + Vt = 64 MB
    if (d_ws != nullptr && ws_size >= need) {
        unsigned short* Kb = (unsigned short*)d_ws;
        unsigned short* Vt = Kb + NEL;
        conv_bf16<<<2048, 256, 0, stream>>>(K, Kb);
        transpose_v<<<NBH * 32, 256, 0, stream>>>(V, Vt);
        dim3 grid((SEQ / BM) * NBH);
        attn_fwd<<<grid, 256, 0, stream>>>(Q, Kb, Vt, O);
    } else {
        dim3 grid((SEQ / BM) * NBH);
        attn_legacy<<<grid, 256, 0, stream>>>(Q, K, V, O);
    }
}

// Round 7
// 640.495 us; speedup vs baseline: 1.9063x; 1.5399x over previous
//
#include <hip/hip_runtime.h>

typedef __attribute__((ext_vector_type(8))) short  short8;   // MFMA A/B frag / 16B bf16 chunk
typedef __attribute__((ext_vector_type(4))) short  short4v;  // 8B store
typedef __attribute__((ext_vector_type(4))) float  float4v;  // MFMA C/D frag
typedef __attribute__((ext_vector_type(4))) float  float4a;  // 16B global load

#define SEQ   2048
#define DHEAD 128
#define NH    32
#define NB    2
#define NBH   (NB * NH)
#define BM    64      // q rows per block (16 per wave x 4 waves)
#define BN    64      // k cols per tile
#define NEL   ((size_t)NBH * SEQ * DHEAD)       // elements per tensor

#define NEG_BIG (-1e30f)

__device__ __forceinline__ unsigned short f2bf(float x) {
    union { float f; unsigned int u; } un; un.f = x;
    unsigned int r = un.u + 0x7fffu + ((un.u >> 16) & 1u);   // round-to-nearest-even
    return (unsigned short)(r >> 16);
}

// XOR swizzle of 16B slots within a 128B bank-row, keyed by row.
__device__ __forceinline__ int fsw(int row) { return (row & 7) ^ ((row >> 3) & 7); }
__device__ __forceinline__ int swz(int row, int colb) { return colb ^ (fsw(row) << 4); }

// ---------------- pre-pass 1: K fp32 -> bf16 elementwise (R4-proven) ----------------
__global__ void conv_bf16(const float* __restrict__ in, unsigned short* __restrict__ out) {
    const size_t n4 = NEL / 4;
    size_t idx = (size_t)blockIdx.x * blockDim.x + threadIdx.x;
    size_t stride = (size_t)gridDim.x * blockDim.x;
    for (size_t i = idx; i < n4; i += stride) {
        float4a v = ((const float4a*)in)[i];
        short4v t;
        t[0] = (short)f2bf(v[0]); t[1] = (short)f2bf(v[1]);
        t[2] = (short)f2bf(v[2]); t[3] = (short)f2bf(v[3]);
        ((short4v*)out)[i] = t;
    }
}

// ---------------- pre-pass 2: V [bh][k][d] fp32 -> Vt [bh][d][k] bf16 (R4-proven) ----------------
__global__ void transpose_v(const float* __restrict__ V, unsigned short* __restrict__ Vt) {
    __shared__ float sT[64 * 132];           // 64 keys x 128 d (+4 pad) = 33 KB
    const int tid = threadIdx.x;
    const int bh  = blockIdx.x >> 5;
    const int k0  = (blockIdx.x & 31) * 64;
    const float* Vp = V + (size_t)bh * SEQ * DHEAD;

    for (int i = tid; i < 64 * 32; i += 256) {
        int r  = i >> 5;
        int c4 = (i & 31) << 2;
        float4a v = *(const float4a*)(Vp + (size_t)(k0 + r) * DHEAD + c4);
        *(float4a*)(&sT[r * 132 + c4]) = v;
    }
    __syncthreads();

    const int d  = tid >> 1;            // 0..127
    const int kh = (tid & 1) * 32;      // 0 or 32
    unsigned short* dst = Vt + ((size_t)bh * DHEAD + d) * SEQ + k0 + kh;
#pragma unroll
    for (int g4 = 0; g4 < 8; ++g4) {
        short4v t;
#pragma unroll
        for (int c = 0; c < 4; ++c)
            t[c] = (short)f2bf(sT[(kh + g4 * 4 + c) * 132 + d]);
        *(short4v*)(dst + g4 * 4) = t;
    }
}

// ---------------- main: flash attention, causal ----------------
// R4 config (BM=64, 256 thr) with the spilling register prefetch REMOVED:
// staging is direct short8 load -> swizzled ds_write from pre-converted bf16
// K / V^T. No f2bf, no transpose, no reg buffers in the hot loop.
// Fragment layouts (guide §3, harness-verified):
//   A-frag: A[m = lane&15][k = (lane>>4)*8 + j]
//   B-frag: B[k = (lane>>4)*8 + j][n = lane&15]
//   C/D   : D[row = (lane>>4)*4 + reg][col = lane&15]
__global__ __launch_bounds__(256, 4)
void attn_fwd(const float* __restrict__ Qg,
              const unsigned short* __restrict__ Kb,
              const unsigned short* __restrict__ Vt,
              float* __restrict__ Og)
{
    // sK [64 key][256B] swz = 16 KB (Q staged here pre-loop)
    // sV [128 d][128B] swz = 16 KB
    // sP 4 waves x 2 KB = 8 KB                 total 40 KB -> 4 blocks/CU
    __shared__ __align__(16) char smem[40960];
    char* sKb = smem;
    char* sVb = smem + 16384;
    char* sPb = smem + 32768;
    char* sQb = sKb;

    const int tid  = threadIdx.x;
    const int w    = tid >> 6;
    const int lane = tid & 63;
    const int quad = lane >> 4;
    const int m16  = lane & 15;

    // XCD-chunked swizzle (grid = 2048 = 8 XCD * 256, bijective)
    const int p  = blockIdx.x;
    const int lb = ((p & 7) << 8) | (p >> 3);
    const int qt = 31 - (lb & 31);     // heavy q-tiles first within each bh
    const int bh = lb >> 5;
    const int q0 = qt * BM;

    const float*          Qp = Qg + (size_t)bh * SEQ * DHEAD;
    const unsigned short* Kp = Kb + (size_t)bh * SEQ * DHEAD;
    const unsigned short* Vp = Vt + (size_t)bh * DHEAD * SEQ;

    // ---- stage Q once (fp32 -> bf16, swizzled) into sK region ----
    for (int i = tid; i < BM * 32; i += 256) {
        int r  = i >> 5;
        int c4 = (i & 31) << 2;
        float4a v = *(const float4a*)(Qp + (size_t)(q0 + r) * DHEAD + c4);
        short4v t;
        t[0] = (short)f2bf(v[0]); t[1] = (short)f2bf(v[1]);
        t[2] = (short)f2bf(v[2]); t[3] = (short)f2bf(v[3]);
        *(short4v*)(sQb + r * 256 + swz(r, c4 * 2)) = t;
    }
    __syncthreads();

    short8 qf[4];
    const int qrow = w * 16 + m16;
#pragma unroll
    for (int kc = 0; kc < 4; ++kc)
        qf[kc] = *(const short8*)(sQb + qrow * 256 + swz(qrow, kc * 64 + quad * 16));
    // first loop-top barrier covers these reads before K staging overwrites sQ.

    float4v accO[8];
#pragma unroll
    for (int i = 0; i < 8; ++i) accO[i] = (float4v){0.f, 0.f, 0.f, 0.f};
    float mst = NEG_BIG, lst = 0.f;
    const float scale = 0.08838834764831845f;   // 1/sqrt(128)
    const int   qglob = q0 + w * 16 + m16;

    for (int kt = 0; kt <= qt; ++kt) {
        const int k0 = kt * BN;
        __syncthreads();   // prev-iter LDS reads done (kt==0: qf reads done)

        // ---- stage K + V^T (bf16): 4x (16B load + 16B swizzled ds_write) each ----
#pragma unroll
        for (int j = 0; j < 4; ++j) {
            int i  = tid + 256 * j;
            int kr = i >> 4, ks = i & 15;        // 64 rows x 16 slots
            short8 kv = *(const short8*)(Kp + (size_t)(k0 + kr) * DHEAD + ks * 8);
            *(short8*)(sKb + kr * 256 + swz(kr, ks * 16)) = kv;
            int vr = i >> 3, vs = i & 7;         // 128 rows x 8 slots
            short8 vv = *(const short8*)(Vp + (size_t)vr * SEQ + k0 + vs * 8);
            *(short8*)(sVb + vr * 128 + swz(vr, vs * 16)) = vv;
        }
        __syncthreads();

        // ---- S^T = K Q^T: accS[nt][r] = S[qglob][k0 + nt*16 + quad*4 + r] ----
        float4v accS[4];
#pragma unroll
        for (int nt = 0; nt < 4; ++nt) accS[nt] = (float4v){0.f, 0.f, 0.f, 0.f};
#pragma unroll
        for (int kc = 0; kc < 4; ++kc)
#pragma unroll
            for (int nt = 0; nt < 4; ++nt) {
                int krow = nt * 16 + m16;
                short8 kf = *(const short8*)(sKb + krow * 256 + swz(krow, kc * 64 + quad * 16));
                accS[nt] = __builtin_amdgcn_mfma_f32_16x16x32_bf16(kf, qf[kc], accS[nt], 0, 0, 0);
            }

        // ---- scale + causal mask (diagonal tile only) ----
        if (kt == qt) {
#pragma unroll
            for (int nt = 0; nt < 4; ++nt)
#pragma unroll
                for (int r = 0; r < 4; ++r) {
                    int key = k0 + nt * 16 + quad * 4 + r;
                    float s = accS[nt][r] * scale;
                    accS[nt][r] = (key > qglob) ? NEG_BIG : s;
                }
        } else {
#pragma unroll
            for (int nt = 0; nt < 4; ++nt)
#pragma unroll
                for (int r = 0; r < 4; ++r) accS[nt][r] *= scale;
        }

        // ---- online softmax (one q-row per lane; cross-quad shfl_xor 16/32) ----
        float mx = accS[0][0];
#pragma unroll
        for (int nt = 0; nt < 4; ++nt)
#pragma unroll
            for (int r = 0; r < 4; ++r) mx = fmaxf(mx, accS[nt][r]);
        mx = fmaxf(mx, __shfl_xor(mx, 16));
        mx = fmaxf(mx, __shfl_xor(mx, 32));
        float mnew  = fmaxf(mst, mx);
        float alpha = __expf(mst - mnew);
        mst = mnew;
        float rs = 0.f;
#pragma unroll
        for (int nt = 0; nt < 4; ++nt)
#pragma unroll
            for (int r = 0; r < 4; ++r) {
                float p2 = __expf(accS[nt][r] - mnew);
                accS[nt][r] = p2;
                rs += p2;
            }
        rs += __shfl_xor(rs, 16);
        rs += __shfl_xor(rs, 32);
        lst = lst * alpha + rs;

        // ---- rescale O ----
        float alphaO[4];
#pragma unroll
        for (int r = 0; r < 4; ++r)
            alphaO[r] = __shfl(alpha, (quad << 4) | (quad * 4 + r));
#pragma unroll
        for (int dt = 0; dt < 8; ++dt)
#pragma unroll
            for (int r = 0; r < 4; ++r) accO[dt][r] *= alphaO[r];

        // ---- P -> per-wave LDS, read back as A-frags ----
        char* pwb = sPb + w * 2048;
#pragma unroll
        for (int nt = 0; nt < 4; ++nt) {
            short4v t;
            t[0] = (short)f2bf(accS[nt][0]); t[1] = (short)f2bf(accS[nt][1]);
            t[2] = (short)f2bf(accS[nt][2]); t[3] = (short)f2bf(accS[nt][3]);
            *(short4v*)(pwb + m16 * 128 + swz(m16, nt * 32 + quad * 8)) = t;
        }
        short8 pf[2];
#pragma unroll
        for (int kc2 = 0; kc2 < 2; ++kc2)
            pf[kc2] = *(const short8*)(pwb + m16 * 128 + swz(m16, kc2 * 64 + quad * 16));

        // ---- O += P V ----
#pragma unroll
        for (int kc2 = 0; kc2 < 2; ++kc2)
#pragma unroll
            for (int dt = 0; dt < 8; ++dt) {
                int vrow = dt * 16 + m16;
                short8 vf = *(const short8*)(sVb + vrow * 128 + swz(vrow, kc2 * 64 + quad * 16));
                accO[dt] = __builtin_amdgcn_mfma_f32_16x16x32_bf16(pf[kc2], vf, accO[dt], 0, 0, 0);
            }
    }

    // ---- epilogue: out[b][q][h*128 + d], fp32 ----
    const int b = bh >> 5;
    const int h = bh & 31;
    float il = 1.0f / lst;
    float invlO[4];
#pragma unroll
    for (int r = 0; r < 4; ++r)
        invlO[r] = __shfl(il, (quad << 4) | (quad * 4 + r));
#pragma unroll
    for (int dt = 0; dt < 8; ++dt)
#pragma unroll
        for (int r = 0; r < 4; ++r) {
            int q = q0 + w * 16 + quad * 4 + r;
            int d = dt * 16 + m16;
            Og[(size_t)(b * SEQ + q) * (NH * DHEAD) + h * DHEAD + d] = accO[dt][r] * invlO[r];
        }
}

// ---------------- fallback (R1 kernel, proven 746 us) if workspace too small ----------------
__global__ __launch_bounds__(256, 4)
void attn_legacy(const float* __restrict__ Qg, const float* __restrict__ Kg,
                 const float* __restrict__ Vg, float* __restrict__ Og)
{
    __shared__ __align__(16) char smem[40960];
    char* sKb = smem;
    char* sVb = smem + 16384;
    char* sPb = smem + 32768;
    char* sQb = sVb;

    const int tid  = threadIdx.x;
    const int w    = tid >> 6;
    const int lane = tid & 63;
    const int quad = lane >> 4;
    const int m16  = lane & 15;

    const int bid = blockIdx.x;
    const int qt  = 31 - (bid & 31);
    const int bh  = bid >> 5;
    const int q0  = qt * 64;

    const float* Qp = Qg + (size_t)bh * SEQ * DHEAD;
    const float* Kp = Kg + (size_t)bh * SEQ * DHEAD;
    const float* Vp = Vg + (size_t)bh * SEQ * DHEAD;

    for (int i = tid; i < 64 * 32; i += 256) {
        int r  = i >> 5;
        int c4 = (i & 31) << 2;
        float4a v = *(const float4a*)(Qp + (size_t)(q0 + r) * DHEAD + c4);
        short4v t;
        t[0] = (short)f2bf(v[0]); t[1] = (short)f2bf(v[1]);
        t[2] = (short)f2bf(v[2]); t[3] = (short)f2bf(v[3]);
        *(short4v*)(sQb + r * 256 + swz(r, c4 * 2)) = t;
    }
    __syncthreads();

    short8 qf[4];
    const int qrow = w * 16 + m16;
#pragma unroll
    for (int kc = 0; kc < 4; ++kc)
        qf[kc] = *(const short8*)(sQb + qrow * 256 + swz(qrow, kc * 64 + quad * 16));

    float4v accO[8];
#pragma unroll
    for (int i = 0; i < 8; ++i) accO[i] = (float4v){0.f, 0.f, 0.f, 0.f};
    float mst = NEG_BIG, lst = 0.f;
    const float scale = 0.08838834764831845f;
    const int   qglob = q0 + w * 16 + m16;

    for (int kt = 0; kt <= qt; ++kt) {
        const int k0 = kt * 64;
        __syncthreads();
        for (int i = tid; i < 64 * 32; i += 256) {
            int r  = i >> 5;
            int c4 = (i & 31) << 2;
            float4a v = *(const float4a*)(Kp + (size_t)(k0 + r) * DHEAD + c4);
            short4v t;
            t[0] = (short)f2bf(v[0]); t[1] = (short)f2bf(v[1]);
            t[2] = (short)f2bf(v[2]); t[3] = (short)f2bf(v[3]);
            *(short4v*)(sKb + r * 256 + swz(r, c4 * 2)) = t;
        }
        for (int i = tid; i < 512; i += 256) {
            int kb = i >> 5;
            int db = i & 31;
            const float* src = Vp + (size_t)(k0 + kb * 4) * DHEAD + db * 4;
            float4a v0 = *(const float4a*)(src);
            float4a v1 = *(const float4a*)(src + DHEAD);
            float4a v2 = *(const float4a*)(src + 2 * DHEAD);
            float4a v3 = *(const float4a*)(src + 3 * DHEAD);
#pragma unroll
            for (int c = 0; c < 4; ++c) {
                short4v t;
                t[0] = (short)f2bf(v0[c]); t[1] = (short)f2bf(v1[c]);
                t[2] = (short)f2bf(v2[c]); t[3] = (short)f2bf(v3[c]);
                int row = db * 4 + c;
                *(short4v*)(sVb + row * 128 + swz(row, kb * 8)) = t;
            }
        }
        __syncthreads();

        float4v accS[4];
#pragma unroll
        for (int nt = 0; nt < 4; ++nt) accS[nt] = (float4v){0.f, 0.f, 0.f, 0.f};
#pragma unroll
        for (int kc = 0; kc < 4; ++kc)
#pragma unroll
            for (int nt = 0; nt < 4; ++nt) {
                int krow = nt * 16 + m16;
                short8 kf = *(const short8*)(sKb + krow * 256 + swz(krow, kc * 64 + quad * 16));
                accS[nt] = __builtin_amdgcn_mfma_f32_16x16x32_bf16(kf, qf[kc], accS[nt], 0, 0, 0);
            }

        if (kt == qt) {
#pragma unroll
            for (int nt = 0; nt < 4; ++nt)
#pragma unroll
                for (int r = 0; r < 4; ++r) {
                    int key = k0 + nt * 16 + quad * 4 + r;
                    float s = accS[nt][r] * scale;
                    accS[nt][r] = (key > qglob) ? NEG_BIG : s;
                }
        } else {
#pragma unroll
            for (int nt = 0; nt < 4; ++nt)
#pragma unroll
                for (int r = 0; r < 4; ++r) accS[nt][r] *= scale;
        }

        float mx = accS[0][0];
#pragma unroll
        for (int nt = 0; nt < 4; ++nt)
#pragma unroll
            for (int r = 0; r < 4; ++r) mx = fmaxf(mx, accS[nt][r]);
        mx = fmaxf(mx, __shfl_xor(mx, 16));
        mx = fmaxf(mx, __shfl_xor(mx, 32));
        float mnew  = fmaxf(mst, mx);
        float alpha = __expf(mst - mnew);
        mst = mnew;
        float rs = 0.f;
#pragma unroll
        for (int nt = 0; nt < 4; ++nt)
#pragma unroll
            for (int r = 0; r < 4; ++r) {
                float p2 = __expf(accS[nt][r] - mnew);
                accS[nt][r] = p2;
                rs += p2;
            }
        rs += __shfl_xor(rs, 16);
        rs += __shfl_xor(rs, 32);
        lst = lst * alpha + rs;

        float alphaO[4];
#pragma unroll
        for (int r = 0; r < 4; ++r)
            alphaO[r] = __shfl(alpha, (quad << 4) | (quad * 4 + r));
#pragma unroll
        for (int dt = 0; dt < 8; ++dt)
#pragma unroll
            for (int r = 0; r < 4; ++r) accO[dt][r] *= alphaO[r];

        char* pwb = sPb + w * 2048;
#pragma unroll
        for (int nt = 0; nt < 4; ++nt) {
            short4v t;
            t[0] = (short)f2bf(accS[nt][0]); t[1] = (short)f2bf(accS[nt][1]);
            t[2] = (short)f2bf(accS[nt][2]); t[3] = (short)f2bf(accS[nt][3]);
            *(short4v*)(pwb + m16 * 128 + swz(m16, nt * 32 + quad * 8)) = t;
        }
        short8 pf[2];
#pragma unroll
        for (int kc2 = 0; kc2 < 2; ++kc2)
            pf[kc2] = *(const short8*)(pwb + m16 * 128 + swz(m16, kc2 * 64 + quad * 16));

#pragma unroll
        for (int kc2 = 0; kc2 < 2; ++kc2)
#pragma unroll
            for (int dt = 0; dt < 8; ++dt) {
                int vrow = dt * 16 + m16;
                short8 vf = *(const short8*)(sVb + vrow * 128 + swz(vrow, kc2 * 64 + quad * 16));
                accO[dt] = __builtin_amdgcn_mfma_f32_16x16x32_bf16(pf[kc2], vf, accO[dt], 0, 0, 0);
            }
    }

    const int b = bh >> 5;
    const int h = bh & 31;
    float il = 1.0f / lst;
    float invlO[4];
#pragma unroll
    for (int r = 0; r < 4; ++r)
        invlO[r] = __shfl(il, (quad << 4) | (quad * 4 + r));
#pragma unroll
    for (int dt = 0; dt < 8; ++dt)
#pragma unroll
        for (int r = 0; r < 4; ++r) {
            int q = q0 + w * 16 + quad * 4 + r;
            int d = dt * 16 + m16;
            Og[(size_t)(b * SEQ + q) * (NH * DHEAD) + h * DHEAD + d] = accO[dt][r] * invlO[r];
        }
}

extern "C" void kernel_launch(void* const* d_in, const int* in_sizes, int n_in,
                              void* d_out, int out_size, void* d_ws, size_t ws_size,
                              hipStream_t stream) {
    const float* Q = (const float*)d_in[0];
    const float* K = (const float*)d_in[1];
    const float* V = (const float*)d_in[2];
    float* O = (float*)d_out;

    const size_t need = 2 * NEL * sizeof(unsigned short);   // Kb + Vt = 64 MB
    if (d_ws != nullptr && ws_size >= need) {
        unsigned short* Kb = (unsigned short*)d_ws;
        unsigned short* Vt = Kb + NEL;
        conv_bf16<<<2048, 256, 0, stream>>>(K, Kb);
        transpose_v<<<NBH * 32, 256, 0, stream>>>(V, Vt);
        dim3 grid(32 * NBH);
        attn_fwd<<<grid, 256, 0, stream>>>(Q, Kb, Vt, O);
    } else {
        dim3 grid(32 * NBH);
        attn_legacy<<<grid, 256, 0, stream>>>(Q, K, V, O);
    }
}